// Round 4
// baseline (1312.773 us; speedup 1.0000x reference)
//
#include <hip/hip_runtime.h>
#include <hip/hip_bf16.h>

// GCN via coarse bucket-binning (512 nodes/bucket, per-XCD sub-regions) + LDS aggregation.
// hs = (x@W)*dinv; S[i] = hs[i] + sum_{src->i} hs[src]; node = relu(dinv[i]*S[i]+b);
// pool mean per graph; logits = pooled@W_cls + b_cls.

#define NNODES 100000
#define NEDGES 3200000
#define FIN    512
#define HID    16
#define NG     64
#define WSTRIDE 20
#define BSH    9                       // 512 nodes per bucket
#define NBUCK  196                     // ceil(100000/512)
#define CAP    2600                    // per (bucket,xcd) region capacity (mean 2050, +12 sigma)
#define NREG   (NBUCK * 8)

// ---------------- zero cursors + graph accumulators ----------------
__global__ void k_zero(int* __restrict__ cur, float* __restrict__ gacc) {
  int i = blockIdx.x * blockDim.x + threadIdx.x;
  if (i < NREG) cur[i] = 0;
  if (i < NG * HID + NG) gacc[i] = 0.0f;
}

// ---------------- bin edges: entry=(src<<9)|dstlow into region (dst>>9, blockIdx&7) ----------------
__global__ __launch_bounds__(256) void k_binA(const int* __restrict__ esrc,
                                              const int* __restrict__ edst,
                                              int* __restrict__ cur,
                                              int* __restrict__ bins) {
  const int t = blockIdx.x * 256 + threadIdx.x;   // 800000 threads, 4 edges each
  const int e0 = t * 4;
  if (e0 >= NEDGES) return;
  const int xcd = blockIdx.x & 7;                 // region selector; disjoint regardless of real mapping
  int4 s4 = *(const int4*)(esrc + e0);
  int4 d4 = *(const int4*)(edst + e0);
#pragma unroll
  for (int j = 0; j < 4; ++j) {
    int s = ((const int*)&s4)[j];
    int d = ((const int*)&d4)[j];
    int r = (d >> BSH) * 8 + xcd;
    int pos = atomicAdd(&cur[r], 1);
    if (pos < CAP)                                 // ~12-sigma guard, never expected
      bins[(size_t)r * CAP + pos] = (s << BSH) | (d & 511);
  }
}

// ---------------- per-bucket degree -> dinv (LDS histogram; replaces global hist+scan) ------------
__global__ __launch_bounds__(256) void k_binDeg(const int* __restrict__ cur,
                                                const int* __restrict__ bins,
                                                float* __restrict__ dinv) {
  __shared__ int deg[512];
  const int b = blockIdx.x;
  for (int i = threadIdx.x; i < 512; i += 256) deg[i] = 0;
  __syncthreads();
  for (int x = 0; x < 8; ++x) {
    const int r = b * 8 + x;
    const int c = min(cur[r], CAP);
    const int* p = bins + (size_t)r * CAP;
    for (int i = threadIdx.x; i < c; i += 256)
      atomicAdd(&deg[p[i] & 511], 1);
  }
  __syncthreads();
  const int base = b << BSH;
  for (int i = threadIdx.x; i < 512; i += 256) {
    int n = base + i;
    if (n < NNODES) dinv[n] = rsqrtf((float)(deg[i] + 1));   // +1 self-loop
  }
}

// ---------------- GEMM: hs[N,16] = (x[N,512] @ W[512,16]) * dinv[row] ----------------
__global__ __launch_bounds__(256) void k_gemm(const float* __restrict__ x,
                                              const float* __restrict__ W,
                                              const float* __restrict__ dinv,
                                              float* __restrict__ hs) {
  __shared__ float Wl[FIN * WSTRIDE];
  const int t = threadIdx.x;
  for (int i = t; i < FIN * 4; i += 256) {
    float4 w = ((const float4*)W)[i];
    *((float4*)&Wl[(i >> 2) * WSTRIDE + (i & 3) * 4]) = w;
  }
  __syncthreads();
  const int lane = t & 63;
  const int ks = lane & 3;
  const int rs = lane >> 2;           // 0..15
  const int gw = (blockIdx.x << 2) + (t >> 6);
  const int base = gw * 32;
  if (base >= NNODES) return;
  const int r0 = base + rs;
  const int r1 = r0 + 16;
  const int c0 = (r0 < NNODES) ? r0 : (NNODES - 1);
  const int c1 = (r1 < NNODES) ? r1 : (NNODES - 1);
  const float* xr0 = x + (size_t)c0 * FIN;
  const float* xr1 = x + (size_t)c1 * FIN;
  float4 acc0[4], acc1[4];
#pragma unroll
  for (int cg = 0; cg < 4; ++cg) {
    acc0[cg] = make_float4(0.f, 0.f, 0.f, 0.f);
    acc1[cg] = make_float4(0.f, 0.f, 0.f, 0.f);
  }
#pragma unroll 4
  for (int ch = 0; ch < 32; ++ch) {
    const int kb = ch * 16 + ks * 4;
    float4 xv0 = *(const float4*)(xr0 + kb);
    float4 xv1 = *(const float4*)(xr1 + kb);
#pragma unroll
    for (int kk = 0; kk < 4; ++kk) {
      const float* wr = &Wl[(kb + kk) * WSTRIDE];
      const float4 w0 = *(const float4*)(wr);
      const float4 w1 = *(const float4*)(wr + 4);
      const float4 w2 = *(const float4*)(wr + 8);
      const float4 w3 = *(const float4*)(wr + 12);
      const float a0 = ((const float*)&xv0)[kk];
      const float a1 = ((const float*)&xv1)[kk];
      acc0[0] += w0 * a0; acc0[1] += w1 * a0; acc0[2] += w2 * a0; acc0[3] += w3 * a0;
      acc1[0] += w0 * a1; acc1[1] += w1 * a1; acc1[2] += w2 * a1; acc1[3] += w3 * a1;
    }
  }
#pragma unroll
  for (int cg = 0; cg < 4; ++cg) {
    float* p0 = (float*)&acc0[cg];
    float* p1 = (float*)&acc1[cg];
#pragma unroll
    for (int j = 0; j < 4; ++j) {
      p0[j] += __shfl_xor(p0[j], 1); p0[j] += __shfl_xor(p0[j], 2);
      p1[j] += __shfl_xor(p1[j], 1); p1[j] += __shfl_xor(p1[j], 2);
    }
  }
  if (ks == 0) {
    if (r0 < NNODES) {
      const float di = dinv[r0];
      float4* o = (float4*)&hs[(size_t)r0 * HID];
      o[0] = make_float4(acc0[0].x*di, acc0[0].y*di, acc0[0].z*di, acc0[0].w*di);
      o[1] = make_float4(acc0[1].x*di, acc0[1].y*di, acc0[1].z*di, acc0[1].w*di);
      o[2] = make_float4(acc0[2].x*di, acc0[2].y*di, acc0[2].z*di, acc0[2].w*di);
      o[3] = make_float4(acc0[3].x*di, acc0[3].y*di, acc0[3].z*di, acc0[3].w*di);
    }
    if (r1 < NNODES) {
      const float di = dinv[r1];
      float4* o = (float4*)&hs[(size_t)r1 * HID];
      o[0] = make_float4(acc1[0].x*di, acc1[0].y*di, acc1[0].z*di, acc1[0].w*di);
      o[1] = make_float4(acc1[1].x*di, acc1[1].y*di, acc1[1].z*di, acc1[1].w*di);
      o[2] = make_float4(acc1[2].x*di, acc1[2].y*di, acc1[2].z*di, acc1[2].w*di);
      o[3] = make_float4(acc1[3].x*di, acc1[3].y*di, acc1[3].z*di, acc1[3].w*di);
    }
  }
}

// ---------------- aggregate per bucket in LDS; fused self-loop+dinv+bias+relu -------------------
__global__ __launch_bounds__(512) void k_aggB(const float* __restrict__ hs,
                                              const int* __restrict__ cur,
                                              const int* __restrict__ bins,
                                              const float* __restrict__ dinv,
                                              const float* __restrict__ bconv,
                                              float* __restrict__ nodeout) {
  __shared__ float acc[512 * HID];                 // 32 KB
  const int b = blockIdx.x;
  for (int i = threadIdx.x; i < 512 * HID; i += 512) acc[i] = 0.f;
  __syncthreads();
  const int w = threadIdx.x >> 6;                  // wave 0..7 -> its xcd sub-region
  const int lane = threadIdx.x & 63;
  const int g = lane >> 4;                         // edge slot 0..3
  const int ch = lane & 15;                        // channel
  const int r = b * 8 + w;
  const int c = min(cur[r], CAP);
  const int* p = bins + (size_t)r * CAP;
  for (int base = 0; base < c; base += 64) {
    const int my = base + lane;
    const int e = (my < c) ? p[my] : 0;            // coalesced chunk load
    const int lim = min(64, c - base);
    for (int i = g; i < lim; i += 4) {
      const int ei = __shfl(e, i);                 // broadcast entry to the 16-lane group
      const int src = ei >> BSH;
      const int dl = ei & 511;
      atomicAdd(&acc[dl * HID + ch], hs[(size_t)src * HID + ch]);  // LDS near-atomic
    }
  }
  __syncthreads();
  const int nb = b << BSH;
  for (int i = threadIdx.x; i < 512 * 4; i += 512) {   // float4 granules
    const int n = nb + (i >> 2);
    if (n >= NNODES) continue;
    const int q = i & 3;
    const float di = dinv[n];
    float4 a = *(float4*)&acc[(i >> 2) * HID + q * 4];
    float4 hv = *(const float4*)&hs[(size_t)n * HID + q * 4];      // self-loop term
    float4 bv = *(const float4*)&bconv[q * 4];
    float4 o;
    o.x = fmaxf((a.x + hv.x) * di + bv.x, 0.f);
    o.y = fmaxf((a.y + hv.y) * di + bv.y, 0.f);
    o.z = fmaxf((a.z + hv.z) * di + bv.z, 0.f);
    o.w = fmaxf((a.w + hv.w) * di + bv.w, 0.f);
    *(float4*)&nodeout[(size_t)n * HID + q * 4] = o;
  }
}

// ---------------- pool: wave-uniform segmented reduce (batch sorted) ----------------
__global__ void k_pool(const float* __restrict__ nodeout, const int* __restrict__ batch,
                       float* __restrict__ gsum, float* __restrict__ gcnt) {
  int i = blockIdx.x * blockDim.x + threadIdx.x;
  const bool valid = i < NNODES;
  const int ic = valid ? i : (NNODES - 1);
  float4 a[4];
#pragma unroll
  for (int cg = 0; cg < 4; ++cg) {
    a[cg] = ((const float4*)nodeout)[ic * 4 + cg];
    if (!valid) a[cg] = make_float4(0.f, 0.f, 0.f, 0.f);
  }
  int g = valid ? batch[ic] : -1;
  int g0 = __shfl(g, 0);
  int g63 = __shfl(g, 63);
  if (g0 == g63 && g0 >= 0) {
#pragma unroll
    for (int cg = 0; cg < 4; ++cg) {
      float* p = (float*)&a[cg];
#pragma unroll
      for (int j = 0; j < 4; ++j) {
        float v = p[j];
        v += __shfl_xor(v, 1);  v += __shfl_xor(v, 2);  v += __shfl_xor(v, 4);
        v += __shfl_xor(v, 8);  v += __shfl_xor(v, 16); v += __shfl_xor(v, 32);
        p[j] = v;
      }
    }
    if ((threadIdx.x & 63) == 0) {
#pragma unroll
      for (int cg = 0; cg < 4; ++cg) {
        float* p = (float*)&a[cg];
        atomicAdd(&gsum[g0 * HID + cg * 4 + 0], p[0]);
        atomicAdd(&gsum[g0 * HID + cg * 4 + 1], p[1]);
        atomicAdd(&gsum[g0 * HID + cg * 4 + 2], p[2]);
        atomicAdd(&gsum[g0 * HID + cg * 4 + 3], p[3]);
      }
      atomicAdd(&gcnt[g0], 64.0f);
    }
  } else if (valid) {
#pragma unroll
    for (int cg = 0; cg < 4; ++cg) {
      float* p = (float*)&a[cg];
      atomicAdd(&gsum[g * HID + cg * 4 + 0], p[0]);
      atomicAdd(&gsum[g * HID + cg * 4 + 1], p[1]);
      atomicAdd(&gsum[g * HID + cg * 4 + 2], p[2]);
      atomicAdd(&gsum[g * HID + cg * 4 + 3], p[3]);
    }
    atomicAdd(&gcnt[g], 1.0f);
  }
}

// ---------------- final ----------------
__global__ void k_final(const float* __restrict__ gsum, const float* __restrict__ gcnt,
                        const float* __restrict__ Wcls, const float* __restrict__ bcls,
                        float* __restrict__ out) {
  int t = threadIdx.x;
  if (t >= NG * 2) return;
  int g = t >> 1, k = t & 1;
  float cnt = fmaxf(gcnt[g], 1.0f);
  float s = 0.f;
#pragma unroll
  for (int c = 0; c < HID; ++c) s += gsum[g * HID + c] * Wcls[c * 2 + k];
  out[t] = s / cnt + bcls[k];
}

extern "C" void kernel_launch(void* const* d_in, const int* in_sizes, int n_in,
                              void* d_out, int out_size, void* d_ws, size_t ws_size,
                              hipStream_t stream) {
  const float* x     = (const float*)d_in[0];
  const float* W     = (const float*)d_in[1];
  const float* bconv = (const float*)d_in[2];
  const float* Wcls  = (const float*)d_in[3];
  const float* bcls  = (const float*)d_in[4];
  const int*   ei    = (const int*)d_in[5];   // [2, E] flat: src then dst
  const int*   batch = (const int*)d_in[6];
  const int* esrc = ei;
  const int* edst = ei + NEDGES;

  char* w = (char*)d_ws;
  float* hs      = (float*)w;  w += (size_t)NNODES * HID * 4;   // 6.4 MB
  float* nodeout = (float*)w;  w += (size_t)NNODES * HID * 4;   // 6.4 MB
  float* dinv    = (float*)w;  w += (size_t)NNODES * 4;         // 400 KB
  int*   cur     = (int*)w;    w += (size_t)NREG * 4;           // 6.3 KB
  float* gsum    = (float*)w;  w += NG * HID * 4;
  float* gcnt    = (float*)w;  w += 256;                        // padded
  int*   bins    = (int*)w;    w += (size_t)NREG * CAP * 4;     // 16.3 MB

  k_zero  <<<7, 256, 0, stream>>>(cur, gsum);
  k_binA  <<<3125, 256, 0, stream>>>(esrc, edst, cur, bins);    // 800000 threads x 4 edges
  k_binDeg<<<NBUCK, 256, 0, stream>>>(cur, bins, dinv);
  k_gemm  <<<(NNODES + 127) / 128, 256, 0, stream>>>(x, W, dinv, hs);
  k_aggB  <<<NBUCK, 512, 0, stream>>>(hs, cur, bins, dinv, bconv, nodeout);
  k_pool  <<<(NNODES + 255) / 256, 256, 0, stream>>>(nodeout, batch, gsum, gcnt);
  k_final <<<1, 128, 0, stream>>>(gsum, gcnt, Wcls, bcls, (float*)d_out);
}

// Round 5
// 811.515 us; speedup vs baseline: 1.6177x; 1.6177x over previous
//
#include <hip/hip_runtime.h>
#include <hip/hip_bf16.h>

// GCN via atomic-free radix partition (256-node buckets, deterministic offsets) + LDS aggregation.
// hs = (x@W)*dinv; S[i] = hs[i] + sum_{e:src->i} hs[src]; node = relu(dinv[i]*S[i]+b);
// pool mean per graph; logits = pooled@W_cls + b_cls.

#define NNODES 100000
#define NEDGES 3200000
#define FIN    512
#define HID    16
#define NG     64
#define WSTRIDE 20
#define BSH    8                        // 256 nodes per bucket
#define NBUCK  391                      // ceil(100000/256)
#define NCB    391                      // scatter chunks; CHUNK=8192 edges each
#define NE4    (NEDGES / 4)             // 800000 int4s

// ---------------- zero graph accumulators ----------------
__global__ void k_zero(float* __restrict__ gacc) {
  int i = blockIdx.x * blockDim.x + threadIdx.x;
  if (i < NG * HID + NG) gacc[i] = 0.0f;
}

// ---------------- pass 1: per-(chunk,bucket) counts via LDS histogram ----------------
__global__ __launch_bounds__(256) void k_count(const int* __restrict__ edst,
                                               int* __restrict__ cnt_mat) {
  __shared__ int cnt[NBUCK];
  const int t = threadIdx.x;
  for (int i = t; i < NBUCK; i += 256) cnt[i] = 0;
  __syncthreads();
  const int b4 = blockIdx.x * 2048;             // CHUNK/4 int4s per block
#pragma unroll
  for (int it = 0; it < 8; ++it) {
    const int idx = b4 + it * 256 + t;
    if (idx < NE4) {
      int4 d4 = ((const int4*)edst)[idx];
      atomicAdd(&cnt[d4.x >> BSH], 1);
      atomicAdd(&cnt[d4.y >> BSH], 1);
      atomicAdd(&cnt[d4.z >> BSH], 1);
      atomicAdd(&cnt[d4.w >> BSH], 1);
    }
  }
  __syncthreads();
  for (int i = t; i < NBUCK; i += 256)
    cnt_mat[blockIdx.x * NBUCK + i] = cnt[i];
}

// ---------------- pass 2a: per-bucket exclusive scan across chunks (in place) ----------------
__global__ __launch_bounds__(512) void k_scanBk(int* __restrict__ cnt_mat,
                                                int* __restrict__ btot) {
  __shared__ int sm[512];
  const int b = blockIdx.x;
  const int t = threadIdx.x;
  int v = (t < NCB) ? cnt_mat[t * NBUCK + b] : 0;
  sm[t] = v; __syncthreads();
#pragma unroll
  for (int d = 1; d < 512; d <<= 1) {
    int x = (t >= d) ? sm[t - d] : 0;
    __syncthreads(); sm[t] += x; __syncthreads();
  }
  if (t < NCB) cnt_mat[t * NBUCK + b] = sm[t] - v;   // exclusive within bucket
  if (t == 511) btot[b] = sm[511];
}

// ---------------- pass 2b: bucket bases ----------------
__global__ __launch_bounds__(512) void k_scanTot(const int* __restrict__ btot,
                                                 int* __restrict__ bbase) {
  __shared__ int sm[512];
  const int t = threadIdx.x;
  int v = (t < NBUCK) ? btot[t] : 0;
  sm[t] = v; __syncthreads();
#pragma unroll
  for (int d = 1; d < 512; d <<= 1) {
    int x = (t >= d) ? sm[t - d] : 0;
    __syncthreads(); sm[t] += x; __syncthreads();
  }
  if (t < NBUCK) bbase[t] = sm[t] - v;
  if (t == 511) bbase[NBUCK] = sm[511];              // = NEDGES
}

// ---------------- pass 3: scatter with LDS cursors (no global atomics) ----------------
__global__ __launch_bounds__(256) void k_scatterD(const int* __restrict__ esrc,
                                                  const int* __restrict__ edst,
                                                  const int* __restrict__ cnt_mat,
                                                  const int* __restrict__ bbase,
                                                  int* __restrict__ bins) {
  __shared__ int lcur[NBUCK];
  const int t = threadIdx.x;
  for (int i = t; i < NBUCK; i += 256)
    lcur[i] = bbase[i] + cnt_mat[blockIdx.x * NBUCK + i];
  __syncthreads();
  const int b4 = blockIdx.x * 2048;
#pragma unroll
  for (int it = 0; it < 8; ++it) {
    const int idx = b4 + it * 256 + t;
    if (idx < NE4) {
      int4 s4 = ((const int4*)esrc)[idx];
      int4 d4 = ((const int4*)edst)[idx];
#pragma unroll
      for (int j = 0; j < 4; ++j) {
        int s = ((const int*)&s4)[j];
        int d = ((const int*)&d4)[j];
        int pos = atomicAdd(&lcur[d >> BSH], 1);     // LDS ticket
        bins[pos] = (s << BSH) | (d & 255);
      }
    }
  }
}

// ---------------- per-bucket degree -> dinv ----------------
__global__ __launch_bounds__(256) void k_binDeg(const int* __restrict__ bins,
                                                const int* __restrict__ bbase,
                                                float* __restrict__ dinv) {
  __shared__ int deg[256];
  const int b = blockIdx.x;
  const int t = threadIdx.x;
  deg[t] = 0;
  __syncthreads();
  const int start = bbase[b], end = bbase[b + 1];
  for (int i = start + t; i < end; i += 256)
    atomicAdd(&deg[bins[i] & 255], 1);
  __syncthreads();
  const int n = (b << BSH) + t;
  if (n < NNODES) dinv[n] = rsqrtf((float)(deg[t] + 1));   // +1 self-loop
}

// ---------------- GEMM: hs[N,16] = (x[N,512] @ W[512,16]) * dinv[row] ----------------
__global__ __launch_bounds__(256) void k_gemm(const float* __restrict__ x,
                                              const float* __restrict__ W,
                                              const float* __restrict__ dinv,
                                              float* __restrict__ hs) {
  __shared__ float Wl[FIN * WSTRIDE];
  const int t = threadIdx.x;
  for (int i = t; i < FIN * 4; i += 256) {
    float4 w = ((const float4*)W)[i];
    *((float4*)&Wl[(i >> 2) * WSTRIDE + (i & 3) * 4]) = w;
  }
  __syncthreads();
  const int lane = t & 63;
  const int ks = lane & 3;
  const int rs = lane >> 2;           // 0..15
  const int gw = (blockIdx.x << 2) + (t >> 6);
  const int base = gw * 32;
  if (base >= NNODES) return;
  const int r0 = base + rs;
  const int r1 = r0 + 16;
  const int c0 = (r0 < NNODES) ? r0 : (NNODES - 1);
  const int c1 = (r1 < NNODES) ? r1 : (NNODES - 1);
  const float* xr0 = x + (size_t)c0 * FIN;
  const float* xr1 = x + (size_t)c1 * FIN;
  float4 acc0[4], acc1[4];
#pragma unroll
  for (int cg = 0; cg < 4; ++cg) {
    acc0[cg] = make_float4(0.f, 0.f, 0.f, 0.f);
    acc1[cg] = make_float4(0.f, 0.f, 0.f, 0.f);
  }
#pragma unroll 4
  for (int ch = 0; ch < 32; ++ch) {
    const int kb = ch * 16 + ks * 4;
    float4 xv0 = *(const float4*)(xr0 + kb);
    float4 xv1 = *(const float4*)(xr1 + kb);
#pragma unroll
    for (int kk = 0; kk < 4; ++kk) {
      const float* wr = &Wl[(kb + kk) * WSTRIDE];
      const float4 w0 = *(const float4*)(wr);
      const float4 w1 = *(const float4*)(wr + 4);
      const float4 w2 = *(const float4*)(wr + 8);
      const float4 w3 = *(const float4*)(wr + 12);
      const float a0 = ((const float*)&xv0)[kk];
      const float a1 = ((const float*)&xv1)[kk];
      acc0[0] += w0 * a0; acc0[1] += w1 * a0; acc0[2] += w2 * a0; acc0[3] += w3 * a0;
      acc1[0] += w0 * a1; acc1[1] += w1 * a1; acc1[2] += w2 * a1; acc1[3] += w3 * a1;
    }
  }
#pragma unroll
  for (int cg = 0; cg < 4; ++cg) {
    float* p0 = (float*)&acc0[cg];
    float* p1 = (float*)&acc1[cg];
#pragma unroll
    for (int j = 0; j < 4; ++j) {
      p0[j] += __shfl_xor(p0[j], 1); p0[j] += __shfl_xor(p0[j], 2);
      p1[j] += __shfl_xor(p1[j], 1); p1[j] += __shfl_xor(p1[j], 2);
    }
  }
  if (ks == 0) {
    if (r0 < NNODES) {
      const float di = dinv[r0];
      float4* o = (float4*)&hs[(size_t)r0 * HID];
      o[0] = make_float4(acc0[0].x*di, acc0[0].y*di, acc0[0].z*di, acc0[0].w*di);
      o[1] = make_float4(acc0[1].x*di, acc0[1].y*di, acc0[1].z*di, acc0[1].w*di);
      o[2] = make_float4(acc0[2].x*di, acc0[2].y*di, acc0[2].z*di, acc0[2].w*di);
      o[3] = make_float4(acc0[3].x*di, acc0[3].y*di, acc0[3].z*di, acc0[3].w*di);
    }
    if (r1 < NNODES) {
      const float di = dinv[r1];
      float4* o = (float4*)&hs[(size_t)r1 * HID];
      o[0] = make_float4(acc1[0].x*di, acc1[0].y*di, acc1[0].z*di, acc1[0].w*di);
      o[1] = make_float4(acc1[1].x*di, acc1[1].y*di, acc1[1].z*di, acc1[1].w*di);
      o[2] = make_float4(acc1[2].x*di, acc1[2].y*di, acc1[2].z*di, acc1[2].w*di);
      o[3] = make_float4(acc1[3].x*di, acc1[3].y*di, acc1[3].z*di, acc1[3].w*di);
    }
  }
}

// ---------------- aggregate per bucket in LDS (reg-batched gathers); fused epilogue -------------
__global__ __launch_bounds__(512) void k_aggB(const float* __restrict__ hs,
                                              const int* __restrict__ bins,
                                              const int* __restrict__ bbase,
                                              const float* __restrict__ dinv,
                                              const float* __restrict__ bconv,
                                              float* __restrict__ nodeout) {
  __shared__ float acc[256 * HID];                 // 16 KB
  const int b = blockIdx.x;
  const int t = threadIdx.x;
  for (int i = t; i < 256 * HID; i += 512) acc[i] = 0.f;
  __syncthreads();
  const int start = bbase[b];
  const int c = bbase[b + 1] - start;
  const int* p = bins + start;
  const int w = t >> 6;                            // wave 0..7
  const int lane = t & 63;
  const int g = lane >> 4;                         // entry group 0..3
  const int ch = lane & 15;                        // channel
  const int per = (c + 7) >> 3;
  const int ws = w * per;
  const int we = min(ws + per, c);
  for (int base = ws; base < we; base += 64) {
    const int m = we - base;                       // valid entries this chunk (cap 64 handled below)
    const int e = (base + lane < we) ? p[base + lane] : 0;
    float v[16]; int dl[16];
#pragma unroll
    for (int j = 0; j < 16; ++j) {
      const int idx = g * 16 + j;
      const int ei = __shfl(e, idx);               // broadcast entry to 16-lane group
      dl[j] = ei & 255;
      const float val = hs[(size_t)(ei >> BSH) * HID + ch];   // 16 independent gathers in flight
      v[j] = (idx < m) ? val : 0.0f;
    }
#pragma unroll
    for (int j = 0; j < 16; ++j)
      atomicAdd(&acc[dl[j] * HID + ch], v[j]);     // LDS near-atomic
  }
  __syncthreads();
  const int nb = b << BSH;
  for (int i = t; i < 256 * 4; i += 512) {         // float4 granules
    const int n = nb + (i >> 2);
    if (n >= NNODES) continue;
    const int q = i & 3;
    const float di = dinv[n];
    float4 a = *(float4*)&acc[(i >> 2) * HID + q * 4];
    float4 hv = *(const float4*)&hs[(size_t)n * HID + q * 4];  // self-loop term
    float4 bv = *(const float4*)&bconv[q * 4];
    float4 o;
    o.x = fmaxf((a.x + hv.x) * di + bv.x, 0.f);
    o.y = fmaxf((a.y + hv.y) * di + bv.y, 0.f);
    o.z = fmaxf((a.z + hv.z) * di + bv.z, 0.f);
    o.w = fmaxf((a.w + hv.w) * di + bv.w, 0.f);
    *(float4*)&nodeout[(size_t)n * HID + q * 4] = o;
  }
}

// ---------------- pool: wave-uniform segmented reduce (batch sorted) ----------------
__global__ void k_pool(const float* __restrict__ nodeout, const int* __restrict__ batch,
                       float* __restrict__ gsum, float* __restrict__ gcnt) {
  int i = blockIdx.x * blockDim.x + threadIdx.x;
  const bool valid = i < NNODES;
  const int ic = valid ? i : (NNODES - 1);
  float4 a[4];
#pragma unroll
  for (int cg = 0; cg < 4; ++cg) {
    a[cg] = ((const float4*)nodeout)[ic * 4 + cg];
    if (!valid) a[cg] = make_float4(0.f, 0.f, 0.f, 0.f);
  }
  int g = valid ? batch[ic] : -1;
  int g0 = __shfl(g, 0);
  int g63 = __shfl(g, 63);
  if (g0 == g63 && g0 >= 0) {
#pragma unroll
    for (int cg = 0; cg < 4; ++cg) {
      float* p = (float*)&a[cg];
#pragma unroll
      for (int j = 0; j < 4; ++j) {
        float v = p[j];
        v += __shfl_xor(v, 1);  v += __shfl_xor(v, 2);  v += __shfl_xor(v, 4);
        v += __shfl_xor(v, 8);  v += __shfl_xor(v, 16); v += __shfl_xor(v, 32);
        p[j] = v;
      }
    }
    if ((threadIdx.x & 63) == 0) {
#pragma unroll
      for (int cg = 0; cg < 4; ++cg) {
        float* p = (float*)&a[cg];
        atomicAdd(&gsum[g0 * HID + cg * 4 + 0], p[0]);
        atomicAdd(&gsum[g0 * HID + cg * 4 + 1], p[1]);
        atomicAdd(&gsum[g0 * HID + cg * 4 + 2], p[2]);
        atomicAdd(&gsum[g0 * HID + cg * 4 + 3], p[3]);
      }
      atomicAdd(&gcnt[g0], 64.0f);
    }
  } else if (valid) {
#pragma unroll
    for (int cg = 0; cg < 4; ++cg) {
      float* p = (float*)&a[cg];
      atomicAdd(&gsum[g * HID + cg * 4 + 0], p[0]);
      atomicAdd(&gsum[g * HID + cg * 4 + 1], p[1]);
      atomicAdd(&gsum[g * HID + cg * 4 + 2], p[2]);
      atomicAdd(&gsum[g * HID + cg * 4 + 3], p[3]);
    }
    atomicAdd(&gcnt[g], 1.0f);
  }
}

// ---------------- final ----------------
__global__ void k_final(const float* __restrict__ gsum, const float* __restrict__ gcnt,
                        const float* __restrict__ Wcls, const float* __restrict__ bcls,
                        float* __restrict__ out) {
  int t = threadIdx.x;
  if (t >= NG * 2) return;
  int g = t >> 1, k = t & 1;
  float cnt = fmaxf(gcnt[g], 1.0f);
  float s = 0.f;
#pragma unroll
  for (int c = 0; c < HID; ++c) s += gsum[g * HID + c] * Wcls[c * 2 + k];
  out[t] = s / cnt + bcls[k];
}

extern "C" void kernel_launch(void* const* d_in, const int* in_sizes, int n_in,
                              void* d_out, int out_size, void* d_ws, size_t ws_size,
                              hipStream_t stream) {
  const float* x     = (const float*)d_in[0];
  const float* W     = (const float*)d_in[1];
  const float* bconv = (const float*)d_in[2];
  const float* Wcls  = (const float*)d_in[3];
  const float* bcls  = (const float*)d_in[4];
  const int*   ei    = (const int*)d_in[5];   // [2, E] flat: src then dst
  const int*   batch = (const int*)d_in[6];
  const int* esrc = ei;
  const int* edst = ei + NEDGES;

  char* w = (char*)d_ws;
  float* hs      = (float*)w;  w += (size_t)NNODES * HID * 4;   // 6.4 MB
  float* nodeout = (float*)w;  w += (size_t)NNODES * HID * 4;   // 6.4 MB
  float* dinv    = (float*)w;  w += (size_t)NNODES * 4;         // 400 KB
  int*   cnt_mat = (int*)w;    w += (size_t)NCB * NBUCK * 4;    // 611 KB
  int*   btot    = (int*)w;    w += (size_t)NBUCK * 4;
  int*   bbase   = (int*)w;    w += (size_t)(NBUCK + 1) * 4;
  float* gsum    = (float*)w;  w += NG * HID * 4;
  float* gcnt    = (float*)w;  w += 256;                        // padded
  int*   bins    = (int*)w;    w += (size_t)NEDGES * 4;         // 12.8 MB (exact)

  k_zero    <<<5, 256, 0, stream>>>(gsum);
  k_count   <<<NCB, 256, 0, stream>>>(edst, cnt_mat);
  k_scanBk  <<<NBUCK, 512, 0, stream>>>(cnt_mat, btot);
  k_scanTot <<<1, 512, 0, stream>>>(btot, bbase);
  k_scatterD<<<NCB, 256, 0, stream>>>(esrc, edst, cnt_mat, bbase, bins);
  k_binDeg  <<<NBUCK, 256, 0, stream>>>(bins, bbase, dinv);
  k_gemm    <<<(NNODES + 127) / 128, 256, 0, stream>>>(x, W, dinv, hs);
  k_aggB    <<<NBUCK, 512, 0, stream>>>(hs, bins, bbase, dinv, bconv, nodeout);
  k_pool    <<<(NNODES + 255) / 256, 256, 0, stream>>>(nodeout, batch, gsum, gcnt);
  k_final   <<<1, 128, 0, stream>>>(gsum, gcnt, Wcls, bcls, (float*)d_out);
}